// Round 10
// baseline (29.622 us; speedup 1.0000x reference)
//
#include <hip/hip_runtime.h>
#include <cfloat>

// Problem constants (fixed by the reference)
#define N_PTS 65536
#define M_PTS 1024
#define BLOCK 256      // 4 waves per block (fine occupancy granularity)
#define QG    256      // queries per group = per wave (4 per lane)
#define WPB   4        // waves per block
#define CGN   16       // chunk-groups (blocks) per query group
#define C     16       // maze points per wave  (WPB*CGN*C = 1024)

typedef float f32x2 __attribute__((ext_vector_type(2)));
typedef float f32x4 __attribute__((ext_vector_type(4)));

// Forced VOP3P packed f32 (2 maze points / instruction), proven in R9.
// (m-q)^2 == (q-m)^2 bit-exactly; op order (dx2+dy2)+dz2 preserved,
// contraction off -> distances bit-identical to the f32 reference.
#define PK_SUB(d, a, b) asm("v_pk_add_f32 %0, %1, %2 neg_lo:[0,1] neg_hi:[0,1]" : "=v"(d) : "v"(a), "v"(b))
#define PK_MUL(d, a, b) asm("v_pk_mul_f32 %0, %1, %2" : "=v"(d) : "v"(a), "v"(b))
#define PK_ADD(d, a, b) asm("v_pk_add_f32 %0, %1, %2" : "=v"(d) : "v"(a), "v"(b))

// R10 hypothesis test: ZERO memory ops in the hot loop. 16 maze points live
// in VGPRs (uniform-address loads, 1 line each, once), 4 queries/lane live
// in VGPRs, inner loop is pure packed VALU. If the ~22us basin survives
// this, it is a fixed launch/latency floor, not a pipe limit.
__global__ __launch_bounds__(BLOCK) void nn_partial(
    const float* __restrict__ ed,     // [N,3]
    const float* __restrict__ mp,     // [M,3]
    float* __restrict__ dpart,        // [4096*256]
    int*   __restrict__ ipart)        // [4096*256]
{
#pragma clang fp contract(off)
    __shared__ float s_d[WPB][QG];    // 4 KB
    __shared__ int   s_i[WPB][QG];    // 4 KB

    const int tid  = threadIdx.x;
    const int lane = tid & 63;
    const int w    = tid >> 6;
    const int qg   = blockIdx.x >> 4;   // query group (256 queries)
    const int cg   = blockIdx.x & 15;   // chunk group
    const int chunk = cg * WPB + w;     // 0..63, 16 maze pts each

    // ---- Prologue: maze chunk -> VGPRs (wave-uniform addrs, 12 lines) ----
    const f32x4* mv = (const f32x4*)(mp + chunk * C * 3);   // 192B aligned
    float mr[48];
    #pragma unroll
    for (int j = 0; j < 12; ++j) *(f32x4*)&mr[4 * j] = mv[j];
    // Transpose AoS -> per-coordinate point-pairs {pt2p, pt2p+1} (48 VGPR).
    f32x2 pmx[8], pmy[8], pmz[8];
    #pragma unroll
    for (int p = 0; p < 8; ++p) {
        pmx[p] = f32x2{mr[6 * p + 0], mr[6 * p + 3]};
        pmy[p] = f32x2{mr[6 * p + 1], mr[6 * p + 4]};
        pmz[p] = f32x2{mr[6 * p + 2], mr[6 * p + 5]};
    }

    // ---- Queries: 4 per lane, 48B contiguous -> 3 x dwordx4 coalesced ----
    const int q0 = qg * QG + lane * 4;
    const f32x4 e0 = *(const f32x4*)&ed[q0 * 3 + 0];  // qa.xyz qb.x
    const f32x4 e1 = *(const f32x4*)&ed[q0 * 3 + 4];  // qb.yz  qc.xy
    const f32x4 e2 = *(const f32x4*)&ed[q0 * 3 + 8];  // qc.z   qd.xyz
    const f32x2 qax = {e0.x, e0.x}, qay = {e0.y, e0.y}, qaz = {e0.z, e0.z};
    const f32x2 qbx = {e0.w, e0.w}, qby = {e1.x, e1.x}, qbz = {e1.y, e1.y};
    const f32x2 qcx = {e1.z, e1.z}, qcy = {e1.w, e1.w}, qcz = {e2.x, e2.x};
    const f32x2 qdx = {e2.y, e2.y}, qdy = {e2.z, e2.z}, qdz = {e2.w, e2.w};

    float dA = FLT_MAX, dB = FLT_MAX, dC = FLT_MAX, dD = FLT_MAX;
    int   iA = 0, iB = 0, iC = 0, iD = 0;   // local index 0..15

    // ---- Hot loop: pure packed VALU, no memory ops, full unroll ----
    #pragma unroll
    for (int p = 0; p < 8; ++p) {
        f32x2 dx, dy, dz, sx, sy, sz, t, dd;
        #define QSTEP(QX, QY, QZ, DV, IV) do {                              \
            PK_SUB(dx, pmx[p], QX); PK_SUB(dy, pmy[p], QY);                 \
            PK_SUB(dz, pmz[p], QZ);                                         \
            PK_MUL(sx, dx, dx); PK_MUL(sy, dy, dy); PK_MUL(sz, dz, dz);     \
            PK_ADD(t, sx, sy); PK_ADD(dd, t, sz);                           \
            if (dd.x < DV) { DV = dd.x; IV = 2 * p; }                       \
            if (dd.y < DV) { DV = dd.y; IV = 2 * p + 1; }                   \
        } while (0)
        QSTEP(qax, qay, qaz, dA, iA);
        QSTEP(qbx, qby, qbz, dB, iB);
        QSTEP(qcx, qcy, qcz, dC, iC);
        QSTEP(qdx, qdy, qdz, dD, iD);
        #undef QSTEP
    }

    // ---- Merge 4 waves (ascending chunk ranges) -> per-(qg,cg) partial ----
    const int gbase = chunk * C;
    s_d[w][lane * 4 + 0] = dA;  s_i[w][lane * 4 + 0] = gbase + iA;
    s_d[w][lane * 4 + 1] = dB;  s_i[w][lane * 4 + 1] = gbase + iB;
    s_d[w][lane * 4 + 2] = dC;  s_i[w][lane * 4 + 2] = gbase + iC;
    s_d[w][lane * 4 + 3] = dD;  s_i[w][lane * 4 + 3] = gbase + iD;
    __syncthreads();

    float dm = s_d[0][tid];
    int   bi = s_i[0][tid];
    #pragma unroll
    for (int j = 1; j < WPB; ++j) {
        const float od = s_d[j][tid];
        const int   ob = s_i[j][tid];
        if (od < dm || (od == dm && ob < bi)) { dm = od; bi = ob; }
    }
    const int slot = blockIdx.x * QG + tid;   // (qg*16+cg)*256+tid
    dpart[slot] = dm;
    ipart[slot] = bi;
}

// Merge the 16 chunk-group partials per query and gather outputs.
__global__ __launch_bounds__(256) void nn_final(
    const float* __restrict__ mp,
    const float* __restrict__ ts,
    const float* __restrict__ dpart,
    const int*   __restrict__ ipart,
    float* __restrict__ out)
{
    const int q = blockIdx.x * 256 + threadIdx.x;
    const int qg = q >> 8, r = q & 255;
    float dm = dpart[(qg * CGN + 0) * QG + r];
    int   bi = ipart[(qg * CGN + 0) * QG + r];
    #pragma unroll
    for (int cgi = 1; cgi < CGN; ++cgi) {
        const float od = dpart[(qg * CGN + cgi) * QG + r];
        const int   ob = ipart[(qg * CGN + cgi) * QG + r];
        // ascending cg = ascending index ranges; strict '<' keeps earlier.
        if (od < dm || (od == dm && ob < bi)) { dm = od; bi = ob; }
    }
    out[q * 3 + 0]     = mp[bi * 3 + 0];
    out[q * 3 + 1]     = mp[bi * 3 + 1];
    out[q * 3 + 2]     = mp[bi * 3 + 2];
    out[N_PTS * 3 + q] = ts[bi];
}

extern "C" void kernel_launch(void* const* d_in, const int* in_sizes, int n_in,
                              void* d_out, int out_size, void* d_ws, size_t ws_size,
                              hipStream_t stream) {
    const float* ed = (const float*)d_in[0];
    const float* mp = (const float*)d_in[1];
    const float* ts = (const float*)d_in[2];
    float* out = (float*)d_out;

    float* dpart = (float*)d_ws;                       // 4096*256 f32 (4 MB)
    int*   ipart = (int*)d_ws + 4096 * QG;             // 4096*256 i32 (4 MB)

    const int grid1 = (N_PTS / QG) * CGN;   // 4096 blocks x 256 thr
    nn_partial<<<grid1, BLOCK, 0, stream>>>(ed, mp, dpart, ipart);

    const int grid2 = N_PTS / 256;          // 256 blocks
    nn_final<<<grid2, 256, 0, stream>>>(mp, ts, dpart, ipart, out);
}

// Round 11
// 27.127 us; speedup vs baseline: 1.0920x; 1.0920x over previous
//
#include <hip/hip_runtime.h>
#include <cfloat>

// Problem constants (fixed by the reference)
#define N_PTS 65536
#define M_PTS 1024
#define BLOCK 512
#define WAVES 8
#define QPL   8          // queries per lane
#define QPB   512        // queries per block (QPL * 64)
#define CPW   16         // maze points per wave (register-resident chunk)
#define NCB   8          // chunk-blocks per query group (1024 / (8*16))

typedef float f32x2 __attribute__((ext_vector_type(2)));
typedef float f32x4 __attribute__((ext_vector_type(4)));

// Forced VOP3P packed f32 (2 maze points / instruction), proven exact in R9:
// (m-q)^2 == (q-m)^2 bit-exactly; op order (dx2+dy2)+dz2 preserved,
// contraction off -> distances bit-identical to the f32 reference.
#define PK_SUB(d,a,b) asm("v_pk_add_f32 %0, %1, %2 neg_lo:[0,1] neg_hi:[0,1]" : "=v"(d) : "v"(a), "v"(b))
#define PK_MUL(d,a,b) asm("v_pk_mul_f32 %0, %1, %2" : "=v"(d) : "v"(a), "v"(b))
#define PK_ADD(d,a,b) asm("v_pk_add_f32 %0, %1, %2" : "=v"(d) : "v"(a), "v"(b))

// R11: ZERO memory ops in the hot loop, with real per-wave work (R10's flaw
// fixed): 16 maze pts live in 48 VGPRs as pk pairs, 8 queries/lane live in
// 24 VGPRs, inner loop = 896 pure packed-VALU instrs. Queries are assigned
// STRIDED (qi*64+lane) so every global load, LDS slot, ws slot and final-
// kernel access is coalesced with no permutation. LDS used only in the
// epilogue merge (conflict-free in both write and read directions).
__global__ __launch_bounds__(BLOCK) void nn_partial(
    const float* __restrict__ ed,     // [N,3]
    const float* __restrict__ mp,     // [M,3]
    float* __restrict__ dpart,        // [NCB][N_PTS]
    int*   __restrict__ ipart)        // [NCB][N_PTS]
{
#pragma clang fp contract(off)
    __shared__ float s_d[WAVES][QPB];   // 16 KB
    __shared__ int   s_i[WAVES][QPB];   // 16 KB

    const int tid  = threadIdx.x;
    const int lane = tid & 63;
    const int w    = tid >> 6;
    const int qg   = blockIdx.x >> 3;   // query group (512 queries), 0..127
    const int cb   = blockIdx.x & 7;    // chunk-block, 0..7
    const int chunk = cb * WAVES + w;   // 0..63; 16 maze pts each

    // ---- Maze chunk -> VGPRs (wave-uniform addrs, 192 B, L1-resident) ----
    float mr[48];
    const f32x4* mv = (const f32x4*)(mp + chunk * (CPW * 3));
    #pragma unroll
    for (int j = 0; j < 12; ++j) *(f32x4*)&mr[4 * j] = mv[j];
    // Transpose AoS -> per-coordinate point-pairs {2p, 2p+1} (48 VGPR).
    f32x2 pmx[8], pmy[8], pmz[8];
    #pragma unroll
    for (int p = 0; p < 8; ++p) {
        pmx[p] = f32x2{mr[6 * p + 0], mr[6 * p + 3]};
        pmy[p] = f32x2{mr[6 * p + 1], mr[6 * p + 4]};
        pmz[p] = f32x2{mr[6 * p + 2], mr[6 * p + 5]};
    }

    // ---- Queries, strided: query(qi) = qg*512 + qi*64 + lane ----
    // Per qi: 3 dword loads, 64 lanes dense over 768 B -> fully coalesced.
    const float* qb = ed + (size_t)qg * QPB * 3;
    float qx[QPL], qy[QPL], qz[QPL];
    #pragma unroll
    for (int qi = 0; qi < QPL; ++qi) {
        const int o = (qi * 64 + lane) * 3;
        qx[qi] = qb[o + 0]; qy[qi] = qb[o + 1]; qz[qi] = qb[o + 2];
    }

    // ---- Hot loop: pure packed VALU, no memory ops, fully unrolled ----
    float dmin[QPL]; int loc[QPL];
    #pragma unroll
    for (int qi = 0; qi < QPL; ++qi) {
        const f32x2 bx = {qx[qi], qx[qi]};
        const f32x2 by = {qy[qi], qy[qi]};
        const f32x2 bz = {qz[qi], qz[qi]};
        float dm = FLT_MAX; int li = 0;
        #pragma unroll
        for (int p = 0; p < 8; ++p) {
            f32x2 dx, dy, dz, sx, sy, sz, t, dd;
            PK_SUB(dx, pmx[p], bx);
            PK_SUB(dy, pmy[p], by);
            PK_SUB(dz, pmz[p], bz);
            PK_MUL(sx, dx, dx); PK_MUL(sy, dy, dy); PK_MUL(sz, dz, dz);
            PK_ADD(t, sx, sy); PK_ADD(dd, t, sz);
            // Ascending local order (2p before 2p+1), strict '<' -> first min.
            if (dd.x < dm) { dm = dd.x; li = 2 * p;     }
            if (dd.y < dm) { dm = dd.y; li = 2 * p + 1; }
        }
        dmin[qi] = dm; loc[qi] = li;
    }

    // ---- Epilogue: publish (conflict-free: bank = lane%32) ----
    #pragma unroll
    for (int qi = 0; qi < QPL; ++qi) {
        s_d[w][qi * 64 + lane] = dmin[qi];
        s_i[w][qi * 64 + lane] = chunk * CPW + loc[qi];
    }
    __syncthreads();

    // Merge 8 waves per slot; slot tid == block-query index (strided map),
    // waves j ascending == maze chunks ascending -> first-argmin tie-break.
    float dm = s_d[0][tid];
    int   bi = s_i[0][tid];
    #pragma unroll
    for (int j = 1; j < WAVES; ++j) {
        const float od = s_d[j][tid];
        const int   ob = s_i[j][tid];
        if (od < dm || (od == dm && ob < bi)) { dm = od; bi = ob; }
    }
    dpart[cb * N_PTS + qg * QPB + tid] = dm;   // coalesced
    ipart[cb * N_PTS + qg * QPB + tid] = bi;
}

// Merge the 8 chunk-block partials per query and gather outputs.
__global__ __launch_bounds__(256) void nn_final(
    const float* __restrict__ mp,
    const float* __restrict__ ts,
    const float* __restrict__ dpart,
    const int*   __restrict__ ipart,
    float* __restrict__ out)
{
    const int q = blockIdx.x * 256 + threadIdx.x;   // global query id
    float dm = dpart[q];
    int   bi = ipart[q];
    #pragma unroll
    for (int cb = 1; cb < NCB; ++cb) {
        const float od = dpart[cb * N_PTS + q];
        const int   ob = ipart[cb * N_PTS + q];
        // ascending cb = ascending maze index ranges; strict '<' keeps first.
        if (od < dm || (od == dm && ob < bi)) { dm = od; bi = ob; }
    }
    out[q * 3 + 0]     = mp[bi * 3 + 0];
    out[q * 3 + 1]     = mp[bi * 3 + 1];
    out[q * 3 + 2]     = mp[bi * 3 + 2];
    out[N_PTS * 3 + q] = ts[bi];
}

extern "C" void kernel_launch(void* const* d_in, const int* in_sizes, int n_in,
                              void* d_out, int out_size, void* d_ws, size_t ws_size,
                              hipStream_t stream) {
    const float* ed = (const float*)d_in[0];
    const float* mp = (const float*)d_in[1];
    const float* ts = (const float*)d_in[2];
    float* out = (float*)d_out;

    float* dpart = (float*)d_ws;                       // 8*65536 f32 (2 MB)
    int*   ipart = (int*)d_ws + NCB * N_PTS;           // 8*65536 i32 (2 MB)

    const int grid1 = (N_PTS / QPB) * NCB;   // 1024 blocks x 512 thr
    nn_partial<<<grid1, BLOCK, 0, stream>>>(ed, mp, dpart, ipart);

    const int grid2 = N_PTS / 256;           // 256 blocks
    nn_final<<<grid2, 256, 0, stream>>>(mp, ts, dpart, ipart, out);
}